// Round 6
// baseline (352.200 us; speedup 1.0000x reference)
//
#include <hip/hip_runtime.h>
#include <cstdint>
#include <cstddef>

// Instant-NGP multires hash encoding, MI355X.
//
// Round-6: round-5 (time-phased levels + x-pair merged gathers + LDS
// transpose) + PPT=2 in the gather. Measured rate 0.35 lines/cyc/CU at 87%
// occupancy ~= in-flight-limited (28 waves x 6 loads / ~400cy latency).
// Two points per thread doubles independent loads per wave (12) to push
// in-flight lines/CU toward the L2 request ceiling.

typedef float f32x2 __attribute__((ext_vector_type(2)));
typedef float f32x4 __attribute__((ext_vector_type(4)));

#define NUM_LEVELS 16
#define BLOCK 256
#define PPT 2
#define CHUNK (BLOCK * PPT)

__global__ __launch_bounds__(BLOCK) void hashenc_gather(
    const float* __restrict__ x,
    const float* __restrict__ table,
    const float* __restrict__ scalings,
    const int* __restrict__ hash_offset,
    const int* __restrict__ tsp,
    float* __restrict__ ws,           // [L][N] f32x2, level-major
    int n_points, int bpl)            // bpl = blocks per level (of CHUNK pts)
{
    // Big/small alternation so slot-boundary straddles co-residence a 4MB
    // slab with a small one.
    static const int perm_arr[NUM_LEVELS] =
        {15, 0, 14, 1, 13, 2, 12, 3, 11, 4, 10, 9, 8, 7, 6, 5};

    const int bid   = (int)blockIdx.x;
    const int slot  = bid / bpl;                    // wave-uniform
    const int level = perm_arr[slot];
    const int t     = (int)threadIdx.x;
    const int nb    = (bid - slot * bpl) * CHUNK + t;

    const float    s    = scalings[level];
    const int      off  = hash_offset[level];
    const uint32_t ts   = (uint32_t)tsp[0];
    const bool     pow2 = (ts & (ts - 1u)) == 0u;   // uniform branch
    const uint32_t mask = ts - 1u;

    const f32x2* tb2 = reinterpret_cast<const f32x2*>(table) + off;
    const f32x4* tb4 = reinterpret_cast<const f32x4*>(table + (size_t)off * 2);
    f32x2* wsl = reinterpret_cast<f32x2*>(ws) + (size_t)level * n_points;

    int  n[PPT];
    bool valid[PPT];
#pragma unroll
    for (int p = 0; p < PPT; ++p) {
        n[p] = nb + p * BLOCK;
        valid[p] = n[p] < n_points;
    }

    if (pow2) {
        uint32_t hf[PPT][4], hc[PPT][4], bf[PPT][4];
        bool     mg[PPT][4];
        float    wcw[PPT][4], wfw[PPT][4];

#pragma unroll
        for (int p = 0; p < PPT; ++p) {
            const int idx = valid[p] ? n[p] : 0;
            const float px = x[idx * 3 + 0];
            const float py = x[idx * 3 + 1];
            const float pz = x[idx * 3 + 2];

            const float sx = px * s, sy = py * s, sz = pz * s;
            const float fxf = floorf(sx), fyf = floorf(sy), fzf = floorf(sz);
            const float tx = sx - fxf, ty = sy - fyf, tz = sz - fzf;

            const uint32_t fxi = (uint32_t)(int)fxf;
            const uint32_t fyi = (uint32_t)(int)fyf;
            const uint32_t fzi = (uint32_t)(int)fzf;
            const uint32_t cxi = (uint32_t)(int)ceilf(sx);
            const uint32_t cyi = (uint32_t)(int)ceilf(sy);
            const uint32_t czi = (uint32_t)(int)ceilf(sz);

            const uint32_t P1 = 2654435761u, P2 = 805459861u;
            const uint32_t hyf = fyi * P1, hyc = cyi * P1;
            const uint32_t hzf = fzi * P2, hzc = czi * P2;

            const uint32_t A[4] = {hyc ^ hzc, hyc ^ hzf, hyf ^ hzc, hyf ^ hzf};
#pragma unroll
            for (int j = 0; j < 4; ++j) {
                hf[p][j] = (fxi ^ A[j]) & mask;
                hc[p][j] = (cxi ^ A[j]) & mask;
                bf[p][j] = hf[p][j] >> 1;
                mg[p][j] = (hc[p][j] >> 1) == bf[p][j];
            }

            const float ux = 1.f - tx, uy = 1.f - ty, uz = 1.f - tz;
            wcw[p][0] = tx * ty * tz;  wfw[p][0] = ux * ty * tz;   // v0 / v3
            wcw[p][1] = tx * uy * tz;  wfw[p][1] = tx * uy * uz;   // v1 / v5
            wcw[p][2] = ux * uy * tz;  wfw[p][2] = ux * uy * uz;   // v2 / v6
            wcw[p][3] = tx * ty * uz;  wfw[p][3] = ux * ty * uz;   // v4 / v7
        }

        // Issue all block loads (2 pts x 4 = 8 dwordx4) back-to-back for MLP.
        f32x4 q[PPT][4];
#pragma unroll
        for (int p = 0; p < PPT; ++p)
#pragma unroll
            for (int j = 0; j < 4; ++j)
                if (valid[p]) q[p][j] = tb4[bf[p][j]];

        // Exec-masked extra loads for unmerged c-corners (~50% of lanes).
        f32x2 el[PPT][4];
#pragma unroll
        for (int p = 0; p < PPT; ++p)
#pragma unroll
            for (int j = 0; j < 4; ++j) {
                el[p][j].x = 0.f; el[p][j].y = 0.f;
                if (valid[p] && !mg[p][j]) el[p][j] = tb2[hc[p][j]];
            }

#pragma unroll
        for (int p = 0; p < PPT; ++p) {
            if (!valid[p]) continue;
            f32x2 acc = {0.f, 0.f};
#pragma unroll
            for (int j = 0; j < 4; ++j) {
                const f32x2 qlo = {q[p][j].x, q[p][j].y};
                const f32x2 qhi = {q[p][j].z, q[p][j].w};
                const f32x2 ef = (hf[p][j] & 1u) ? qhi : qlo;
                const f32x2 eh = (hc[p][j] & 1u) ? qhi : qlo;
                const f32x2 ec = mg[p][j] ? eh : el[p][j];
                acc.x = fmaf(wfw[p][j], ef.x, acc.x);
                acc.y = fmaf(wfw[p][j], ef.y, acc.y);
                acc.x = fmaf(wcw[p][j], ec.x, acc.x);
                acc.y = fmaf(wcw[p][j], ec.y, acc.y);
            }
            __builtin_nontemporal_store(acc, wsl + n[p]);
        }
    } else {
        // Generic path (non-pow2): plain 8 gathers per point.
#pragma unroll
        for (int p = 0; p < PPT; ++p) {
            if (!valid[p]) continue;
            const float px = x[n[p]*3], py = x[n[p]*3+1], pz = x[n[p]*3+2];
            const float sx = px*s, sy = py*s, sz = pz*s;
            const float fxf = floorf(sx), fyf = floorf(sy), fzf = floorf(sz);
            const float tx = sx-fxf, ty = sy-fyf, tz = sz-fzf;
            const uint32_t fxi = (uint32_t)(int)fxf, fyi = (uint32_t)(int)fyf, fzi = (uint32_t)(int)fzf;
            const uint32_t cxi = (uint32_t)(int)ceilf(sx), cyi = (uint32_t)(int)ceilf(sy), czi = (uint32_t)(int)ceilf(sz);
            const uint32_t P1 = 2654435761u, P2 = 805459861u;
            const uint32_t hyf = fyi*P1, hyc = cyi*P1, hzf = fzi*P2, hzc = czi*P2;
            uint32_t h[8] = {cxi^hyc^hzc, cxi^hyc^hzf, cxi^hyf^hzc, fxi^hyc^hzc,
                             cxi^hyf^hzf, fxi^hyc^hzf, fxi^hyf^hzc, fxi^hyf^hzf};
            f32x2 f[8];
#pragma unroll
            for (int c = 0; c < 8; ++c) f[c] = tb2[h[c] % ts];
            const float ux = 1.f-tx, uy = 1.f-ty, uz = 1.f-tz;
            float w[8] = {tx*ty*tz, tx*uy*tz, ux*uy*tz, ux*ty*tz,
                          tx*ty*uz, tx*uy*uz, ux*uy*uz, ux*ty*uz};
            f32x2 acc = {0.f, 0.f};
#pragma unroll
            for (int c = 0; c < 8; ++c) {
                acc.x = fmaf(w[c], f[c].x, acc.x);
                acc.y = fmaf(w[c], f[c].y, acc.y);
            }
            __builtin_nontemporal_store(acc, wsl + n[p]);
        }
    }
}

// ws [L][N] f32x2 -> out [N][L] f32x2 via LDS tile.
__global__ __launch_bounds__(BLOCK) void hashenc_transpose(
    const float* __restrict__ ws, float* __restrict__ out, int n_points)
{
    __shared__ f32x2 tile[NUM_LEVELS][BLOCK + 2];

    const int base = (int)blockIdx.x * BLOCK;
    const int t    = (int)threadIdx.x;
    const int n    = base + t;
    const bool full = (base + BLOCK) <= n_points;

    if (full) {
#pragma unroll
        for (int l = 0; l < NUM_LEVELS; ++l)
            tile[l][t] = __builtin_nontemporal_load(
                reinterpret_cast<const f32x2*>(ws) + (size_t)l * n_points + n);
        __syncthreads();

        const int p0 = t >> 3;
        const int j  = t & 7;
        f32x4* o = reinterpret_cast<f32x4*>(out + (size_t)base * (NUM_LEVELS * 2));
#pragma unroll
        for (int i = 0; i < 8; ++i) {
            const int p = i * 32 + p0;
            const f32x2 a = tile[2 * j][p];
            const f32x2 b = tile[2 * j + 1][p];
            f32x4 v;
            v.x = a.x; v.y = a.y; v.z = b.x; v.w = b.y;
            __builtin_nontemporal_store(v, o + i * BLOCK + t);
        }
    } else if (n < n_points) {
        f32x2 v[NUM_LEVELS];
#pragma unroll
        for (int l = 0; l < NUM_LEVELS; ++l)
            v[l] = reinterpret_cast<const f32x2*>(ws)[(size_t)l * n_points + n];
        f32x4* o = reinterpret_cast<f32x4*>(out + (size_t)n * (NUM_LEVELS * 2));
#pragma unroll
        for (int i = 0; i < 8; ++i) {
            f32x4 w;
            w.x = v[2*i].x;   w.y = v[2*i].y;
            w.z = v[2*i+1].x; w.w = v[2*i+1].y;
            __builtin_nontemporal_store(w, o + i);
        }
    }
}

// Fallback (ws too small): direct strided store.
__global__ __launch_bounds__(BLOCK) void hashenc_direct(
    const float* __restrict__ x,
    const float* __restrict__ table,
    const float* __restrict__ scalings,
    const int* __restrict__ hash_offset,
    const int* __restrict__ tsp,
    float* __restrict__ out,
    int n_points)
{
    const int tid = blockIdx.x * BLOCK + (int)threadIdx.x;
    if (tid >= n_points * NUM_LEVELS) return;
    const int n = tid >> 4, l = tid & 15;

    const float s = scalings[l];
    const int off = hash_offset[l];
    const uint32_t ts = (uint32_t)tsp[0];
    const bool pow2 = (ts & (ts - 1u)) == 0u;
    const uint32_t mask = ts - 1u;

    const float sx = x[n*3]*s, sy = x[n*3+1]*s, sz = x[n*3+2]*s;
    const float fxf = floorf(sx), fyf = floorf(sy), fzf = floorf(sz);
    const float tx = sx - fxf, ty = sy - fyf, tz = sz - fzf;
    const uint32_t fxi = (uint32_t)(int)fxf, fyi = (uint32_t)(int)fyf, fzi = (uint32_t)(int)fzf;
    const uint32_t cxi = (uint32_t)(int)ceilf(sx), cyi = (uint32_t)(int)ceilf(sy), czi = (uint32_t)(int)ceilf(sz);
    const uint32_t P1 = 2654435761u, P2 = 805459861u;
    const uint32_t hyf = fyi*P1, hyc = cyi*P1, hzf = fzi*P2, hzc = czi*P2;
    uint32_t h[8] = {cxi^hyc^hzc, cxi^hyc^hzf, cxi^hyf^hzc, fxi^hyc^hzc,
                     cxi^hyf^hzf, fxi^hyc^hzf, fxi^hyf^hzc, fxi^hyf^hzf};
    const f32x2* tb = reinterpret_cast<const f32x2*>(table) + off;
    f32x2 f[8];
#pragma unroll
    for (int c = 0; c < 8; ++c) f[c] = tb[pow2 ? (h[c] & mask) : (h[c] % ts)];
    const float ux = 1.f-tx, uy = 1.f-ty, uz = 1.f-tz;
    float w[8] = {tx*ty*tz, tx*uy*tz, ux*uy*tz, ux*ty*tz,
                  tx*ty*uz, tx*uy*uz, ux*uy*uz, ux*ty*uz};
    f32x2 acc = {0.f, 0.f};
#pragma unroll
    for (int c = 0; c < 8; ++c) {
        acc.x = fmaf(w[c], f[c].x, acc.x);
        acc.y = fmaf(w[c], f[c].y, acc.y);
    }
    __builtin_nontemporal_store(acc, reinterpret_cast<f32x2*>(out) + tid);
}

extern "C" void kernel_launch(void* const* d_in, const int* in_sizes, int n_in,
                              void* d_out, int out_size, void* d_ws, size_t ws_size,
                              hipStream_t stream) {
    const float* x           = (const float*)d_in[0];
    const float* hash_table  = (const float*)d_in[1];
    const float* scalings    = (const float*)d_in[2];
    const int*   hash_offset = (const int*)d_in[3];
    const int*   table_size  = (const int*)d_in[4];
    float*       out         = (float*)d_out;

    const int n_points = in_sizes[0] / 3;
    const int bpl      = (n_points + CHUNK - 1) / CHUNK;   // blocks per level
    const size_t ws_needed = (size_t)n_points * NUM_LEVELS * 2 * sizeof(float);

    if (ws_size >= ws_needed) {
        hashenc_gather<<<NUM_LEVELS * bpl, BLOCK, 0, stream>>>(
            x, hash_table, scalings, hash_offset, table_size,
            (float*)d_ws, n_points, bpl);
        const int bpt = (n_points + BLOCK - 1) / BLOCK;
        hashenc_transpose<<<bpt, BLOCK, 0, stream>>>(
            (const float*)d_ws, out, n_points);
    } else {
        const int total = n_points * NUM_LEVELS;
        hashenc_direct<<<(total + BLOCK - 1) / BLOCK, BLOCK, 0, stream>>>(
            x, hash_table, scalings, hash_offset, table_size, out, n_points);
    }
}